// Round 12
// baseline (101.166 us; speedup 1.0000x reference)
//
#include <hip/hip_runtime.h>
#include <cstdint>

// B=16384 rows, K=2048 centers, D=128, T=1.0
// Outputs (flat, f32): out[B*D], center[K*D], label[B]
#define NB 16384
#define NK 2048
#define ND 128
#define MARGINF 0.11f    // 0.10 (R3-proven bf16 window) + f16 residual-cache slack
#define CAP 6144
#define XPITCH 132       // padded LDS x-row stride (floats)

typedef __attribute__((ext_vector_type(8))) short bf16x8;
typedef __attribute__((ext_vector_type(4))) float f32x4;
typedef unsigned long long u64;

__device__ __forceinline__ unsigned short f2bf(float f) {
    unsigned u = __float_as_uint(f);
    u += 0x7fffu + ((u >> 16) & 1u);          // round-to-nearest-even
    return (unsigned short)(u >> 16);
}

union HU { _Float16 h; unsigned short s; };

// ---------------------------------------------------------------------------
// Prep (392 blocks): cbf B-frag layout | c2 (R1-identical chain) | center copy
// ---------------------------------------------------------------------------
__global__ __launch_bounds__(256)
void prep(const float* __restrict__ c,
          unsigned short* __restrict__ cbf,
          float* __restrict__ c2,
          float* __restrict__ out_center) {
    const int bid = blockIdx.x;
    const int tid = threadIdx.x;
    if (bid < 128) {
        int t = bid * 256 + tid;              // 0..32767
        int lane = t & 63, s = (t >> 6) & 3, kt = t >> 8;
        int kc = kt * 16 + (lane & 15);
        int d0 = s * 32 + (lane >> 4) * 8;
        const float* src = c + (long)kc * ND + d0;
        unsigned short h[8];
#pragma unroll
        for (int j = 0; j < 8; ++j) h[j] = f2bf(src[j]);
        int4 pk;
        pk.x = h[0] | (h[1] << 16); pk.y = h[2] | (h[3] << 16);
        pk.z = h[4] | (h[5] << 16); pk.w = h[6] | (h[7] << 16);
        ((int4*)cbf)[t] = pk;
    } else if (bid < 136) {
        int k = (bid - 128) * 256 + tid;      // 0..2047
        const float4* row = (const float4*)(c + (long)k * ND);
        float s = 0.f;
#pragma unroll 8
        for (int i = 0; i < ND / 4; ++i) {
            float4 v = row[i];
            s += v.x * v.x + v.y * v.y + v.z * v.z + v.w * v.w;
        }
        c2[k] = s;
    } else {
        int i = (bid - 136) * 256 + tid;      // 0..K*D/4-1
        ((float4*)out_center)[i] = ((const float4*)c)[i];
    }
}

// ---------------------------------------------------------------------------
// Main: 512 blocks x 512 threads (8 waves), R3 geometry (the proven optimum:
// 2 blocks/CU, 4 waves/SIMD). Block owns 32 rows x ALL 2048 k. Wave w covers
// k in [w*256, w*256+256) in 4 chunks of 4 16-k tiles.
//
// SINGLE MFMA sweep; sweep 2 replaced by a REGISTER scan: per tile each lane
// packs its 8 d2 values as f16 residuals r = d2 - x2row (range +-4, f16 abs
// err <=0.002; raw d2 ~ 128 would lose 0.25 ulp in 16 bits -> residual is
// the trick) into rc[4][4] (16 VGPRs). After each chunk: block-reduce the
// running per-(row,reg) mins (shfls OUTSIDE the hot loop -- R6 lesson) ->
// per-slot threshold -> scan rc (zero loads, zero MFMA) collecting
// candidates. Halves cbf L2 traffic AND MFMA work at unchanged occupancy --
// the thing R5/R11's geometry changes failed to deliver.
//
// Correctness: threshold = bmin_now + MARGINF where bmin_now >= bmin_final
// (monotone atomicMin) -> collection is a superset of the tight set for any
// race interleaving. For argmin k*: |d2~ - d2| window 0.10 (R3-proven) +
// 2x f16 cache err (0.004) < MARGINF=0.11 -> k* always collected. Exact
// fp32 refine chain (R1-identical) prunes -> labels exact. CAP 6144 absorbs
// partial-threshold inflation (chunks 1-3 use looser-than-final bmin).
//
// History: R1 49 | R2 spill 131 | R3 38 | R4 ILP neutral | R5 43.5 |
// R6 shfl-in-loop 110 | R8 loose-collect WRONG | R9 u8-LDS-cache 42.5 |
// R10 8w/SIMD 58 | R11 64r@4w 43 | R12: register f16-residual cache (this).
// ---------------------------------------------------------------------------
__global__ __launch_bounds__(512, 4)
void kmeans_main(const float* __restrict__ x,
                 const float* __restrict__ center,
                 const unsigned short* __restrict__ cbf,
                 const float* __restrict__ c2,
                 float* __restrict__ out,
                 float* __restrict__ label_out) {
    __shared__ float xs[32 * XPITCH];         // 16.9 KB fp32 x rows
    __shared__ float c2s[NK];                 // 8 KB center norms
    __shared__ float x2s[32];
    __shared__ unsigned bmin[32];
    __shared__ u64 best[32];
    __shared__ unsigned short buf[CAP];       // 12 KB candidate list
    __shared__ unsigned cnt;

    const int tid  = threadIdx.x;
    const int lane = tid & 63;
    const int wave = __builtin_amdgcn_readfirstlane(tid >> 6);  // 0..7
    const long rb  = (long)blockIdx.x * 32;

    // ---- stage x rows -> LDS (coalesced, 2 float4/thread) ----
    {
        int idx = tid;
        int r = idx >> 5, q = idx & 31;
        ((float4*)(xs + r * XPITCH))[q] = ((const float4*)(x + (rb + r) * ND))[q];
        idx = tid + 512;
        r = idx >> 5; q = idx & 31;
        ((float4*)(xs + r * XPITCH))[q] = ((const float4*)(x + (rb + r) * ND))[q];
    }
    ((float4*)c2s)[tid] = ((const float4*)c2)[tid];
    if (tid < 32) { bmin[tid] = 0x7f800000u; best[tid] = ~0ULL; }
    if (tid == 0) cnt = 0;
    __syncthreads();

    // ---- x2 per row: chain IDENTICAL to R1 (float2, 6-level butterfly) ----
    for (int i = 0; i < 4; ++i) {
        int r = wave * 4 + i;
        float2 v = *(const float2*)(xs + r * XPITCH + lane * 2);
        float s = v.x * v.x + v.y * v.y;
#pragma unroll
        for (int off = 32; off; off >>= 1) s += __shfl_xor(s, off, 64);
        if (lane == 0) x2s[r] = s;
    }
    __syncthreads();

    // ---- A-frags into registers ----
    bf16x8 af[2][4];
#pragma unroll
    for (int rt = 0; rt < 2; ++rt)
#pragma unroll
        for (int s = 0; s < 4; ++s) {
            const float* p = xs + (rt * 16 + (lane & 15)) * XPITCH
                               + s * 32 + (lane >> 4) * 8;
            float4 u0 = ((const float4*)p)[0];
            float4 u1 = ((const float4*)p)[1];
            bf16x8 a;
            a[0] = (short)f2bf(u0.x); a[1] = (short)f2bf(u0.y);
            a[2] = (short)f2bf(u0.z); a[3] = (short)f2bf(u0.w);
            a[4] = (short)f2bf(u1.x); a[5] = (short)f2bf(u1.y);
            a[6] = (short)f2bf(u1.z); a[7] = (short)f2bf(u1.w);
            af[rt][s] = a;
        }

    float x2p[2][4];
#pragma unroll
    for (int rt = 0; rt < 2; ++rt)
#pragma unroll
        for (int reg = 0; reg < 4; ++reg)
            x2p[rt][reg] = x2s[rt * 16 + (lane >> 4) * 4 + reg];

    const bf16x8* CF = (const bf16x8*)cbf;
    const int kt0 = wave * 16;                // wave covers tiles kt0..kt0+15

    float rmin[2][4];
#pragma unroll
    for (int rt = 0; rt < 2; ++rt)
#pragma unroll
        for (int reg = 0; reg < 4; ++reg) rmin[rt][reg] = __builtin_inff();

    for (int chunk = 0; chunk < 4; ++chunk) {
        unsigned rc[4][4];                    // f16x2 residual cache (16 VGPR)

        // ---- sweep this chunk's 4 tiles (FULL unroll: rc must stay in regs) ----
#pragma unroll
        for (int ct = 0; ct < 4; ++ct) {
            const int kt = kt0 + chunk * 4 + ct;
            bf16x8 bfr[4];
#pragma unroll
            for (int s = 0; s < 4; ++s) bfr[s] = CF[(kt * 4 + s) * 64 + lane];
            f32x4 acc0 = {0.f,0.f,0.f,0.f}, acc1 = {0.f,0.f,0.f,0.f};
#pragma unroll
            for (int s = 0; s < 4; ++s) {
                acc0 = __builtin_amdgcn_mfma_f32_16x16x32_bf16(af[0][s], bfr[s], acc0, 0,0,0);
                acc1 = __builtin_amdgcn_mfma_f32_16x16x32_bf16(af[1][s], bfr[s], acc1, 0,0,0);
            }
            float c2v = c2s[kt * 16 + (lane & 15)];
#pragma unroll
            for (int reg = 0; reg < 4; ++reg) {
                float d20 = fmaf(-2.f, acc0[reg], x2p[0][reg] + c2v);
                float d21 = fmaf(-2.f, acc1[reg], x2p[1][reg] + c2v);
                rmin[0][reg] = fminf(rmin[0][reg], d20);
                rmin[1][reg] = fminf(rmin[1][reg], d21);
                HU a; a.h = (_Float16)(d20 - x2p[0][reg]);
                HU b; b.h = (_Float16)(d21 - x2p[1][reg]);
                rc[ct][reg] = (unsigned)a.s | ((unsigned)b.s << 16);
            }
        }

        // ---- block-reduce running mins -> bmin (OUTSIDE hot loop) ----
#pragma unroll
        for (int rt = 0; rt < 2; ++rt)
#pragma unroll
            for (int reg = 0; reg < 4; ++reg) {
                float v = rmin[rt][reg];
#pragma unroll
                for (int off = 1; off < 16; off <<= 1)
                    v = fminf(v, __shfl_xor(v, off, 64));
                if ((lane & 15) == 0)         // d2 >= 0 -> uint order == float order
                    atomicMin(&bmin[rt * 16 + (lane >> 4) * 4 + reg], __float_as_uint(v));
            }
        __syncthreads();                      // bmin (this chunk's info) visible

        // ---- residual-space thresholds; scan the register cache ----
        float rthr[2][4];
#pragma unroll
        for (int rt = 0; rt < 2; ++rt)
#pragma unroll
            for (int reg = 0; reg < 4; ++reg)
                rthr[rt][reg] = __uint_as_float(bmin[rt * 16 + (lane >> 4) * 4 + reg])
                                + MARGINF - x2p[rt][reg];

#pragma unroll
        for (int ct = 0; ct < 4; ++ct) {
            const int col = (kt0 + chunk * 4 + ct) * 16 + (lane & 15);
#pragma unroll
            for (int reg = 0; reg < 4; ++reg) {
                unsigned v = rc[ct][reg];
                HU a; a.s = (unsigned short)(v & 0xffffu);
                HU b; b.s = (unsigned short)(v >> 16);
                float lo = (float)a.h, hi = (float)b.h;
                if (lo <= rthr[0][reg]) {
                    unsigned rloc = (lane >> 4) * 4 + reg;         // rt=0
                    unsigned idx = atomicAdd(&cnt, 1u);
                    if (idx < CAP) buf[idx] = (unsigned short)((rloc << 11) | col);
                }
                if (hi <= rthr[1][reg]) {
                    unsigned rloc = 16 + (lane >> 4) * 4 + reg;    // rt=1
                    unsigned idx = atomicAdd(&cnt, 1u);
                    if (idx < CAP) buf[idx] = (unsigned short)((rloc << 11) | col);
                }
            }
        }
    }
    __syncthreads();

    // ---- exact refine: fp32 chain IDENTICAL to R1 (serial fmaf dot,
    //      t=x2+c2, fmaf(-2,dot,t), max, sqrt; u64 key -> lowest k on tie) ----
    unsigned n = cnt; if (n > CAP) n = CAP;
    for (unsigned i = tid; i < n; i += 512) {
        unsigned pc = buf[i];
        int rloc = pc >> 11, col = pc & (NK - 1);
        const float* xr = xs + rloc * XPITCH;
        const float* cr = center + (long)col * ND;
        float dot = 0.f;
#pragma unroll 8
        for (int d = 0; d < ND; ++d) dot = fmaf(xr[d], cr[d], dot);
        float t = x2s[rloc] + c2s[col];
        float f = fmaxf(fmaf(-2.0f, dot, t), 0.0f);
        float s = __builtin_sqrtf(f);
        u64 key = ((u64)__float_as_uint(s) << 32) | (unsigned)col;
        atomicMin(&best[rloc], key);
    }
    __syncthreads();

    // ---- direct output: gather center[bk] per row + label ----
    for (int i = 0; i < 4; ++i) {
        int rloc = wave * 4 + i;
        int bk = (int)(best[rloc] & 0xffffffffULL);
        float2 cv = ((const float2*)(center + (long)bk * ND))[lane];
        ((float2*)(out + (rb + rloc) * ND))[lane] = cv;
        if (lane == 0) label_out[rb + rloc] = (float)bk;
    }
}

// ---------------------------------------------------------------------------
extern "C" void kernel_launch(void* const* d_in, const int* in_sizes, int n_in,
                              void* d_out, int out_size, void* d_ws, size_t ws_size,
                              hipStream_t stream) {
    const float* x      = (const float*)d_in[0];   // [B][D]
    const float* center = (const float*)d_in[1];   // [K][D]
    float* out = (float*)d_out;

    float* out_x      = out;                        // [B*D]
    float* out_center = out + (long)NB * ND;        // [K*D]
    float* out_label  = out_center + (long)NK * ND; // [B]

    // Workspace: cbf[K*D]u16 (0.5MB), c2[K]f32
    unsigned short* cbf = (unsigned short*)d_ws;
    float* c2 = (float*)(cbf + (size_t)NK * ND);

    prep<<<392, 256, 0, stream>>>(center, cbf, c2, out_center);
    kmeans_main<<<NB / 32, 512, 0, stream>>>(x, center, cbf, c2,
                                             out_x, out_label);
}

// Round 13
// 96.047 us; speedup vs baseline: 1.0533x; 1.0533x over previous
//
#include <hip/hip_runtime.h>
#include <cstdint>

// B=16384 rows, K=2048 centers, D=128, T=1.0
// Outputs (flat, f32): out[B*D], center[K*D], label[B]
#define NB 16384
#define NK 2048
#define ND 128
#define MARGIN 0.10f
#define CAP 2048
#define XPITCH 132   // padded LDS x-row stride (floats): breaks bank aliasing

typedef __attribute__((ext_vector_type(8))) short bf16x8;
typedef __attribute__((ext_vector_type(4))) float f32x4;
typedef unsigned long long u64;

__device__ __forceinline__ unsigned short f2bf(float f) {
    unsigned u = __float_as_uint(f);
    u += 0x7fffu + ((u >> 16) & 1u);          // round-to-nearest-even
    return (unsigned short)(u >> 16);
}

// ---------------------------------------------------------------------------
// Prep (136 blocks):
//  [0,128)    cbf: center -> bf16 MFMA B-frag layout
//  [128,136)  c2 (chain identical to R1)
//  (center passthrough copy moved into kmeans_main -- overlaps with compute)
// ---------------------------------------------------------------------------
__global__ __launch_bounds__(256)
void prep(const float* __restrict__ c,
          unsigned short* __restrict__ cbf,
          float* __restrict__ c2) {
    const int bid = blockIdx.x;
    const int tid = threadIdx.x;
    if (bid < 128) {
        int t = bid * 256 + tid;              // 0..32767
        int lane = t & 63, s = (t >> 6) & 3, kt = t >> 8;
        int kc = kt * 16 + (lane & 15);
        int d0 = s * 32 + (lane >> 4) * 8;
        const float* src = c + (long)kc * ND + d0;
        unsigned short h[8];
#pragma unroll
        for (int j = 0; j < 8; ++j) h[j] = f2bf(src[j]);
        int4 pk;
        pk.x = h[0] | (h[1] << 16); pk.y = h[2] | (h[3] << 16);
        pk.z = h[4] | (h[5] << 16); pk.w = h[6] | (h[7] << 16);
        ((int4*)cbf)[t] = pk;
    } else {
        int k = (bid - 128) * 256 + tid;      // 0..2047
        const float4* row = (const float4*)(c + (long)k * ND);
        float s = 0.f;
#pragma unroll 8
        for (int i = 0; i < ND / 4; ++i) {
            float4 v = row[i];
            s += v.x * v.x + v.y * v.y + v.z * v.z + v.w * v.w;
        }
        c2[k] = s;
    }
}

// ---------------------------------------------------------------------------
// Main: 512 blocks x 512 threads (8 waves). Block owns 32 rows x ALL 2048 k
// -> block min IS the global min. Wave w covers k in [w*256, w*256+256).
// Two MFMA sweeps (min, then filter) + exact fp32 refine (R1-identical
// chain); direct out/label writes. Also copies its 1/512 slice of center ->
// out_center (fold of prep's passthrough: overlaps copy with compute).
//
// SETTLED GEOMETRY (12 rounds of evidence): 512x512, 32 rows, 4 waves/SIMD.
//  - TLP: 2 w/SIMD latency-bound (R1 49us); 8 w/SIMD LDS/barrier contention
//    (R10 58us); 4 w/SIMD optimal (R3 38us).
//  - ILP: 1-deep B-frag prefetch neutral (R4) -- latency already TLP-covered.
//  - Traffic: halving the cbf L2 stream does NOT help (R5/R11 geometry,
//    R9 LDS-cache, R12 reg-cache: all 42-43us vs 38) -- sweep 2's re-reads
//    are warm and its MFMAs overlap; collection machinery costs more than
//    the recompute it saves. Kernel is latency-structured, not BW-bound.
//  - Forcing VGPR bins below the live set spills catastrophically (R2).
//  - Cross-lane shfl reductions must stay OUT of the hot loop (R6).
// ---------------------------------------------------------------------------
__global__ __launch_bounds__(512, 4)
void kmeans_main(const float* __restrict__ x,
                 const float* __restrict__ center,
                 const unsigned short* __restrict__ cbf,
                 const float* __restrict__ c2,
                 float* __restrict__ out,
                 float* __restrict__ out_center,
                 float* __restrict__ label_out) {
    __shared__ float xs[32 * XPITCH];         // 16.9 KB fp32 x rows
    __shared__ float c2s[NK];                 // 8 KB center norms
    __shared__ float x2s[32];
    __shared__ unsigned bmin[32];
    __shared__ u64 best[32];
    __shared__ unsigned buf[CAP];             // 8 KB candidate list
    __shared__ unsigned cnt;

    const int tid  = threadIdx.x;
    const int lane = tid & 63;
    const int wave = __builtin_amdgcn_readfirstlane(tid >> 6);  // 0..7
    const long rb  = (long)blockIdx.x * 32;

    // ---- stage x rows -> LDS (coalesced, 2 float4/thread) ----
    {
        int idx = tid;                        // float4 index 0..1023
        int r = idx >> 5, q = idx & 31;
        ((float4*)(xs + r * XPITCH))[q] = ((const float4*)(x + (rb + r) * ND))[q];
        idx = tid + 512;
        r = idx >> 5; q = idx & 31;
        ((float4*)(xs + r * XPITCH))[q] = ((const float4*)(x + (rb + r) * ND))[q];
    }
    // ---- stage c2 -> LDS (4 floats/thread, coalesced) ----
    ((float4*)c2s)[tid] = ((const float4*)c2)[tid];
    // ---- folded prep-copy: this block's slice of center -> out_center ----
    if (tid < 128) {
        long ci = (long)blockIdx.x * 128 + tid;     // float4 index, 512*128 = 64K total
        ((float4*)out_center)[ci] = ((const float4*)center)[ci];
    }
    if (tid < 32) { bmin[tid] = 0x7f800000u; best[tid] = ~0ULL; }
    if (tid == 0) cnt = 0;
    __syncthreads();

    // ---- x2 per row: chain IDENTICAL to R1 (float2, 6-level butterfly) ----
    for (int i = 0; i < 4; ++i) {
        int r = wave * 4 + i;
        float2 v = *(const float2*)(xs + r * XPITCH + lane * 2);
        float s = v.x * v.x + v.y * v.y;
#pragma unroll
        for (int off = 32; off; off >>= 1) s += __shfl_xor(s, off, 64);
        if (lane == 0) x2s[r] = s;
    }
    __syncthreads();

    // ---- A-frags into registers (reused by both sweeps) ----
    bf16x8 af[2][4];
#pragma unroll
    for (int rt = 0; rt < 2; ++rt)
#pragma unroll
        for (int s = 0; s < 4; ++s) {
            const float* p = xs + (rt * 16 + (lane & 15)) * XPITCH
                               + s * 32 + (lane >> 4) * 8;
            float4 u0 = ((const float4*)p)[0];
            float4 u1 = ((const float4*)p)[1];
            bf16x8 a;
            a[0] = (short)f2bf(u0.x); a[1] = (short)f2bf(u0.y);
            a[2] = (short)f2bf(u0.z); a[3] = (short)f2bf(u0.w);
            a[4] = (short)f2bf(u1.x); a[5] = (short)f2bf(u1.y);
            a[6] = (short)f2bf(u1.z); a[7] = (short)f2bf(u1.w);
            af[rt][s] = a;
        }

    float x2p[2][4];
#pragma unroll
    for (int rt = 0; rt < 2; ++rt)
#pragma unroll
        for (int reg = 0; reg < 4; ++reg)
            x2p[rt][reg] = x2s[rt * 16 + (lane >> 4) * 4 + reg];

    const bf16x8* CF = (const bf16x8*)cbf;
    const int kbase = wave * 256;
    const int kt0   = kbase >> 4;

    // ---- sweep 1: min over this wave's 256 k (1-deep B-frag prefetch) ----
    float rmin[2][4];
#pragma unroll
    for (int rt = 0; rt < 2; ++rt)
#pragma unroll
        for (int reg = 0; reg < 4; ++reg) rmin[rt][reg] = __builtin_inff();

    {
        bf16x8 b0 = CF[(kt0 * 4 + 0) * 64 + lane];
        bf16x8 b1 = CF[(kt0 * 4 + 1) * 64 + lane];
        bf16x8 b2 = CF[(kt0 * 4 + 2) * 64 + lane];
        bf16x8 b3 = CF[(kt0 * 4 + 3) * 64 + lane];
#pragma unroll 1
        for (int ct = 0; ct < 16; ++ct) {
            const int kt  = kt0 + ct;
            const int ktn = kt0 + ((ct + 1) & 15);      // wraps; last iter reloads tile 0 (unused)
            bf16x8 n0 = CF[(ktn * 4 + 0) * 64 + lane];
            bf16x8 n1 = CF[(ktn * 4 + 1) * 64 + lane];
            bf16x8 n2 = CF[(ktn * 4 + 2) * 64 + lane];
            bf16x8 n3 = CF[(ktn * 4 + 3) * 64 + lane];
            f32x4 acc0 = {0.f,0.f,0.f,0.f}, acc1 = {0.f,0.f,0.f,0.f};
            acc0 = __builtin_amdgcn_mfma_f32_16x16x32_bf16(af[0][0], b0, acc0, 0,0,0);
            acc1 = __builtin_amdgcn_mfma_f32_16x16x32_bf16(af[1][0], b0, acc1, 0,0,0);
            acc0 = __builtin_amdgcn_mfma_f32_16x16x32_bf16(af[0][1], b1, acc0, 0,0,0);
            acc1 = __builtin_amdgcn_mfma_f32_16x16x32_bf16(af[1][1], b1, acc1, 0,0,0);
            acc0 = __builtin_amdgcn_mfma_f32_16x16x32_bf16(af[0][2], b2, acc0, 0,0,0);
            acc1 = __builtin_amdgcn_mfma_f32_16x16x32_bf16(af[1][2], b2, acc1, 0,0,0);
            acc0 = __builtin_amdgcn_mfma_f32_16x16x32_bf16(af[0][3], b3, acc0, 0,0,0);
            acc1 = __builtin_amdgcn_mfma_f32_16x16x32_bf16(af[1][3], b3, acc1, 0,0,0);
            float c2v = c2s[kt * 16 + (lane & 15)];
#pragma unroll
            for (int reg = 0; reg < 4; ++reg) {
                rmin[0][reg] = fminf(rmin[0][reg], fmaf(-2.f, acc0[reg], x2p[0][reg] + c2v));
                rmin[1][reg] = fminf(rmin[1][reg], fmaf(-2.f, acc1[reg], x2p[1][reg] + c2v));
            }
            b0 = n0; b1 = n1; b2 = n2; b3 = n3;
        }
    }

    // cross-lane min over the 16 cols (lane&15 group), then block combine
#pragma unroll
    for (int rt = 0; rt < 2; ++rt)
#pragma unroll
        for (int reg = 0; reg < 4; ++reg) {
            float v = rmin[rt][reg];
#pragma unroll
            for (int off = 1; off < 16; off <<= 1)
                v = fminf(v, __shfl_xor(v, off, 64));
            if ((lane & 15) == 0)             // d2 >= 0 -> uint order == float order
                atomicMin(&bmin[rt * 16 + (lane >> 4) * 4 + reg], __float_as_uint(v));
        }
    __syncthreads();

    float thr[2][4];
#pragma unroll
    for (int rt = 0; rt < 2; ++rt)
#pragma unroll
        for (int reg = 0; reg < 4; ++reg)
            thr[rt][reg] = __uint_as_float(bmin[rt * 16 + (lane >> 4) * 4 + reg]) + MARGIN;

    // ---- sweep 2: recompute, filter candidates within MARGIN of block min ----
    {
        bf16x8 b0 = CF[(kt0 * 4 + 0) * 64 + lane];
        bf16x8 b1 = CF[(kt0 * 4 + 1) * 64 + lane];
        bf16x8 b2 = CF[(kt0 * 4 + 2) * 64 + lane];
        bf16x8 b3 = CF[(kt0 * 4 + 3) * 64 + lane];
#pragma unroll 1
        for (int ct = 0; ct < 16; ++ct) {
            const int kt  = kt0 + ct;
            const int ktn = kt0 + ((ct + 1) & 15);
            bf16x8 n0 = CF[(ktn * 4 + 0) * 64 + lane];
            bf16x8 n1 = CF[(ktn * 4 + 1) * 64 + lane];
            bf16x8 n2 = CF[(ktn * 4 + 2) * 64 + lane];
            bf16x8 n3 = CF[(ktn * 4 + 3) * 64 + lane];
            f32x4 acc0 = {0.f,0.f,0.f,0.f}, acc1 = {0.f,0.f,0.f,0.f};
            acc0 = __builtin_amdgcn_mfma_f32_16x16x32_bf16(af[0][0], b0, acc0, 0,0,0);
            acc1 = __builtin_amdgcn_mfma_f32_16x16x32_bf16(af[1][0], b0, acc1, 0,0,0);
            acc0 = __builtin_amdgcn_mfma_f32_16x16x32_bf16(af[0][1], b1, acc0, 0,0,0);
            acc1 = __builtin_amdgcn_mfma_f32_16x16x32_bf16(af[1][1], b1, acc1, 0,0,0);
            acc0 = __builtin_amdgcn_mfma_f32_16x16x32_bf16(af[0][2], b2, acc0, 0,0,0);
            acc1 = __builtin_amdgcn_mfma_f32_16x16x32_bf16(af[1][2], b2, acc1, 0,0,0);
            acc0 = __builtin_amdgcn_mfma_f32_16x16x32_bf16(af[0][3], b3, acc0, 0,0,0);
            acc1 = __builtin_amdgcn_mfma_f32_16x16x32_bf16(af[1][3], b3, acc1, 0,0,0);
            float c2v = c2s[kt * 16 + (lane & 15)];
            const int col = kt * 16 + (lane & 15);
#pragma unroll
            for (int reg = 0; reg < 4; ++reg) {
                float d20 = fmaf(-2.f, acc0[reg], x2p[0][reg] + c2v);
                if (d20 <= thr[0][reg]) {
                    unsigned rloc = (lane >> 4) * 4 + reg;          // rt=0
                    unsigned idx = atomicAdd(&cnt, 1u);
                    if (idx < CAP) buf[idx] = (rloc << 11) | (unsigned)col;
                }
                float d21 = fmaf(-2.f, acc1[reg], x2p[1][reg] + c2v);
                if (d21 <= thr[1][reg]) {
                    unsigned rloc = 16 + (lane >> 4) * 4 + reg;     // rt=1
                    unsigned idx = atomicAdd(&cnt, 1u);
                    if (idx < CAP) buf[idx] = (rloc << 11) | (unsigned)col;
                }
            }
            b0 = n0; b1 = n1; b2 = n2; b3 = n3;
        }
    }
    __syncthreads();

    // ---- exact refine: fp32 chain IDENTICAL to R1 (serial fmaf dot,
    //      t=x2+c2, fmaf(-2,dot,t), max, sqrt; u64 key -> lowest k on tie) ----
    unsigned n = cnt; if (n > CAP) n = CAP;
    for (unsigned i = tid; i < n; i += 512) {
        unsigned pc = buf[i];
        int rloc = pc >> 11, col = pc & (NK - 1);
        const float* xr = xs + rloc * XPITCH;
        const float* cr = center + (long)col * ND;
        float dot = 0.f;
#pragma unroll 8
        for (int d = 0; d < ND; ++d) dot = fmaf(xr[d], cr[d], dot);
        float t = x2s[rloc] + c2s[col];
        float f = fmaxf(fmaf(-2.0f, dot, t), 0.0f);
        float s = __builtin_sqrtf(f);
        u64 key = ((u64)__float_as_uint(s) << 32) | (unsigned)col;
        atomicMin(&best[rloc], key);
    }
    __syncthreads();

    // ---- direct output: gather center[bk] per row + label ----
    for (int i = 0; i < 4; ++i) {
        int rloc = wave * 4 + i;
        int bk = (int)(best[rloc] & 0xffffffffULL);
        float2 cv = ((const float2*)(center + (long)bk * ND))[lane];
        ((float2*)(out + (rb + rloc) * ND))[lane] = cv;
        if (lane == 0) label_out[rb + rloc] = (float)bk;
    }
}

// ---------------------------------------------------------------------------
extern "C" void kernel_launch(void* const* d_in, const int* in_sizes, int n_in,
                              void* d_out, int out_size, void* d_ws, size_t ws_size,
                              hipStream_t stream) {
    const float* x      = (const float*)d_in[0];   // [B][D]
    const float* center = (const float*)d_in[1];   // [K][D]
    float* out = (float*)d_out;

    float* out_x      = out;                        // [B*D]
    float* out_center = out + (long)NB * ND;        // [K*D]
    float* out_label  = out_center + (long)NK * ND; // [B]

    // Workspace: cbf[K*D]u16 (0.5MB), c2[K]f32
    unsigned short* cbf = (unsigned short*)d_ws;
    float* c2 = (float*)(cbf + (size_t)NK * ND);

    prep<<<136, 256, 0, stream>>>(center, cbf, c2);
    kmeans_main<<<NB / 32, 512, 0, stream>>>(x, center, cbf, c2,
                                             out_x, out_center, out_label);
}